// Round 4
// baseline (359.511 us; speedup 1.0000x reference)
//
#include <hip/hip_runtime.h>
#include <hip/hip_bf16.h>

typedef __hip_bfloat16 bf16;
typedef __attribute__((ext_vector_type(8))) short short8;
typedef __attribute__((ext_vector_type(4))) float floatx4;
typedef __attribute__((ext_vector_type(4))) short shortx4;

static constexpr int BATCH = 4;
static constexpr int CH    = 512;   // C
static constexpr int SEQ   = 4096;  // H*W
static constexpr int DM    = 512;   // model dim

__device__ __forceinline__ void gload16(const void* g, void* l) {
  __builtin_amdgcn_global_load_lds(
      (const __attribute__((address_space(1))) unsigned int*)g,
      (__attribute__((address_space(3))) unsigned int*)l,
      16, 0, 0);
}

// ---------------------------------------------------------------------------
// Weight fp32 -> bf16 conversion (4 matrices of 512x512)
// ---------------------------------------------------------------------------
__global__ __launch_bounds__(256) void cvt_weights(
    const float* __restrict__ w0, const float* __restrict__ w1,
    const float* __restrict__ w2, const float* __restrict__ w3,
    bf16* __restrict__ out) {
  const float* src = (blockIdx.y == 0) ? w0 : (blockIdx.y == 1) ? w1
                   : (blockIdx.y == 2) ? w2 : w3;
  int idx = blockIdx.x * 256 + threadIdx.x;
  out[(long)blockIdx.y * (DM * CH) + idx] = __float2bfloat16(src[idx]);
}

// ---------------------------------------------------------------------------
// x (b,c,s) fp32 -> xT (b,s,c) bf16, 64x64 LDS tiles
// ---------------------------------------------------------------------------
__global__ __launch_bounds__(256) void transpose_cvt(
    const float* __restrict__ x, bf16* __restrict__ xT) {
  __shared__ float tile[64][65];
  const int s0 = blockIdx.x * 64, c0 = blockIdx.y * 64;
  const float* xb = x + (long)blockIdx.z * CH * SEQ;
  bf16* xTb = xT + (long)blockIdx.z * SEQ * CH;
  const int t = threadIdx.x;
  const int sl = t & 63, cq = t >> 6;
  #pragma unroll
  for (int i = 0; i < 16; ++i) {
    int cl = cq * 16 + i;
    tile[cl][sl] = xb[(long)(c0 + cl) * SEQ + s0 + sl];
  }
  __syncthreads();
  const int cl2 = t & 63, sq = t >> 6;
  #pragma unroll
  for (int i = 0; i < 16; ++i) {
    int sl2 = sq * 16 + i;
    xTb[(long)(s0 + sl2) * CH + c0 + cl2] = __float2bfloat16(tile[cl2][sl2]);
  }
}

// ---------------------------------------------------------------------------
// gemm_qk: 256x256 tile, BK=64, 8 waves 2Mx4N, per-wave 128x64. 4 phases per
// K-tile (qm,kc); HALF-TILE staged double buffer with counted vmcnt (T4):
//   issue during tile t: p0->B0' p1->B1' p2->A0' p3->A1' (halves of t+1,
//   A-half-qm = rows {qm*64+0..63, qm*64+128..191} = exactly what phase
//   (qm,*) reads).
//   waits: p1-end vmcnt(4) (retire A1 of current tile before p2 reads it);
//   p3-end vmcnt(2) (retire B0',B1',A0'; A1' stays in flight - its LDS
//   region is disjoint from phases 0-1 reads). Never drains to 0.
// T1 XCD swizzle, T2 XOR swizzle, T5 setprio. bf16 out = acc*scale.
// Requires: M,N % 256 == 0, K % 64 == 0, K >= 128.
// ---------------------------------------------------------------------------
__global__ __launch_bounds__(512, 2) void gemm_qk(
    const bf16* __restrict__ A, long sAz,
    const bf16* __restrict__ B, long sBz,
    bf16* __restrict__ C, long sCz,
    float scale, int K, int ldc) {
  __shared__ __align__(16) bf16 As[2][256 * 64];
  __shared__ __align__(16) bf16 Bs[2][256 * 64];

  int id = blockIdx.x + gridDim.x * (blockIdx.y + gridDim.y * blockIdx.z);
  int nwg = gridDim.x * gridDim.y * gridDim.z;
  int sid = ((nwg & 7) == 0) ? ((id & 7) * (nwg >> 3) + (id >> 3)) : id;
  const int bx = sid % gridDim.x;
  const int by = (sid / gridDim.x) % gridDim.y;
  const int bz = sid / (gridDim.x * gridDim.y);

  const int tid = threadIdx.x;
  const long lK = K;
  const bf16* Ab = A + (long)bz * sAz + (long)by * 256 * lK;
  const bf16* Bb = B + (long)bz * sBz + (long)bx * 256 * lK;

  const int w = tid >> 6, lane = tid & 63;
  const int wr = w >> 2, wc = w & 3;          // 2 x 4 wave grid
  const int l16 = lane & 15, quad = lane >> 4;

  const int srow = tid >> 3;                  // 0..63
  const int sp = tid & 7;                     // physical 16B slot
  const int slog = (sp ^ (srow & 7)) << 3;    // pre-swizzled source column

  const int pA0 = (quad ^ (l16 & 7)) << 3;
  const int pA1 = pA0 ^ 32;

  // stage one half-tile: rows {h*64 + r*128 + srow, r=0,1}. LDS dest
  // row*128 + sp*16 stays wave-uniform-base + lane*16 (gload_lds constraint).
  auto stageAh = [&](int buf, int kt, int h) {
    #pragma unroll
    for (int r = 0; r < 2; ++r) {
      const int row = h * 64 + r * 128 + srow;
      gload16(Ab + (long)kt * 64 + (long)row * lK + slog,
              (char*)(&As[buf][0]) + row * 128 + sp * 16);
    }
  };
  auto stageBh = [&](int buf, int kt, int h) {
    #pragma unroll
    for (int r = 0; r < 2; ++r) {
      const int row = h * 64 + r * 128 + srow;
      gload16(Bb + (long)kt * 64 + (long)row * lK + slog,
              (char*)(&Bs[buf][0]) + row * 128 + sp * 16);
    }
  };

  floatx4 acc[8][4];
  #pragma unroll
  for (int m = 0; m < 8; ++m)
    #pragma unroll
    for (int n = 0; n < 4; ++n) acc[m][n] = (floatx4)(0.0f);

  const int nk = K >> 6;
  // prologue: tile 0, order B0,B1,A0,A1; wait all but A1 (steady-state entry)
  stageBh(0, 0, 0); stageBh(0, 0, 1);
  stageAh(0, 0, 0); stageAh(0, 0, 1);
  asm volatile("s_waitcnt vmcnt(2)" ::: "memory");
  __builtin_amdgcn_s_barrier();

  for (int t = 0; t < nk; ++t) {
    const int cur = t & 1, nxt = cur ^ 1;
    const bf16* __restrict__ Al = &As[cur][0];
    const bf16* __restrict__ Bl = &Bs[cur][0];
    const bool more = (t + 1 < nk);
    short8 a[4], b[2][4];
    #pragma unroll
    for (int p = 0; p < 4; ++p) {
      const int qm = p >> 1, kc = p & 1;
      const int poff = kc ? pA1 : pA0;
      #pragma unroll
      for (int i = 0; i < 4; ++i) {
        const int ar = wr * 128 + qm * 64 + i * 16 + l16;
        a[i] = *(const short8*)(Al + ar * 64 + poff);
      }
      if (qm == 0) {
        #pragma unroll
        for (int j = 0; j < 4; ++j) {
          const int br = wc * 64 + j * 16 + l16;
          b[kc][j] = *(const short8*)(Bl + br * 64 + poff);
        }
      }
      if (more) {
        if (p == 0)      stageBh(nxt, t + 1, 0);
        else if (p == 1) stageBh(nxt, t + 1, 1);
        else if (p == 2) stageAh(nxt, t + 1, 0);
        else             stageAh(nxt, t + 1, 1);
      }
      __builtin_amdgcn_s_barrier();
      __builtin_amdgcn_s_setprio(1);
      #pragma unroll
      for (int i = 0; i < 4; ++i)
        #pragma unroll
        for (int j = 0; j < 4; ++j)
          acc[qm * 4 + i][j] = __builtin_amdgcn_mfma_f32_16x16x32_bf16(
              a[i], b[kc][j], acc[qm * 4 + i][j], 0, 0, 0);
      __builtin_amdgcn_s_setprio(0);
      if (p == 1) {
        // retire A1 of CURRENT tile before phase 2 reads half-1
        if (more) asm volatile("s_waitcnt vmcnt(4)" ::: "memory");
        else      asm volatile("s_waitcnt vmcnt(0)" ::: "memory");
      } else if (p == 3 && more) {
        // tile boundary: retire B0',B1',A0'; keep A1' in flight
        asm volatile("s_waitcnt vmcnt(2)" ::: "memory");
      }
      __builtin_amdgcn_s_barrier();
    }
  }

  // epilogue: scale + bf16 store, row-major
  bf16* Cb = C + (long)bz * sCz;
  const int rbase = by * 256 + wr * 128 + quad * 4;
  const int cbase = bx * 256 + wc * 64 + l16;
  #pragma unroll
  for (int m = 0; m < 8; ++m) {
    const int row = rbase + m * 16;
    #pragma unroll
    for (int n = 0; n < 4; ++n) {
      const int col = cbase + n * 16;
      floatx4 v = acc[m][n];
      #pragma unroll
      for (int r = 0; r < 4; ++r)
        Cb[(long)(row + r) * ldc + col] = __float2bfloat16(v[r] * scale);
    }
  }
}

// ---------------------------------------------------------------------------
// gemm_bn128: 256x128 tile, BK=64, 8 waves in 4Mx2N grid, per-wave 64x64.
// 2 phases per K-tile; TRIPLE-buffered LDS + counted vmcnt(6) (t+2 staging).
// MODE 0: bf16 = acc + bias[col], C[row*ldc+col]
// MODE 1: bf16 = acc + bias[col], transposed C[col*ldc+row]
// MODE 2: bf16 = acc * scale,     C[row*ldc+col]
// MODE 4: f32  = acc + bias[col], transposed C[col*ldc+row]
// Requires: M % 256 == 0, N % 128 == 0, K % 64 == 0, K >= 256.
// ---------------------------------------------------------------------------
template <int MODE>
__global__ __launch_bounds__(512, 2) void gemm_bn128(
    const bf16* __restrict__ A, long sAz,
    const bf16* __restrict__ B, long sBz,
    void* __restrict__ Cv, long sCz,
    const float* __restrict__ bias, float scale,
    int K, int ldc) {
  __shared__ __align__(16) bf16 As[3][256 * 64];
  __shared__ __align__(16) bf16 Bs[3][128 * 64];

  int id = blockIdx.x + gridDim.x * (blockIdx.y + gridDim.y * blockIdx.z);
  int nwg = gridDim.x * gridDim.y * gridDim.z;
  int sid = ((nwg & 7) == 0) ? ((id & 7) * (nwg >> 3) + (id >> 3)) : id;
  const int bx = sid % gridDim.x;
  const int by = (sid / gridDim.x) % gridDim.y;
  const int bz = sid / (gridDim.x * gridDim.y);

  const int tid = threadIdx.x;
  const long lK = K;
  const bf16* Ab = A + (long)bz * sAz + (long)by * 256 * lK;
  const bf16* Bb = B + (long)bz * sBz + (long)bx * 128 * lK;

  const int w = tid >> 6, lane = tid & 63;
  const int wr = w >> 1, wc = w & 1;          // 4 x 2 wave grid
  const int l16 = lane & 15, quad = lane >> 4;

  const int srow = tid >> 3;
  const int sp = tid & 7;
  const int slog = (sp ^ (srow & 7)) << 3;    // pre-swizzled source column

  const int pA0 = (quad ^ (l16 & 7)) << 3;
  const int pA1 = pA0 ^ 32;

  auto stageA = [&](int buf, int kt) {
    const bf16* s = Ab + (long)kt * 64 + (long)srow * lK + slog;
    char* d = (char*)(&As[buf][0]) + tid * 16;
    #pragma unroll
    for (int r = 0; r < 4; ++r)
      gload16(s + (long)(r * 64) * lK, d + r * 8192);
  };
  auto stageB = [&](int buf, int kt) {
    const bf16* s = Bb + (long)kt * 64 + (long)srow * lK + slog;
    char* d = (char*)(&Bs[buf][0]) + tid * 16;
    #pragma unroll
    for (int r = 0; r < 2; ++r)
      gload16(s + (long)(r * 64) * lK, d + r * 8192);
  };

  floatx4 acc[4][4];
  #pragma unroll
  for (int m = 0; m < 4; ++m)
    #pragma unroll
    for (int n = 0; n < 4; ++n) acc[m][n] = (floatx4)(0.0f);

  const int nk = K >> 6;
  // prologue: stage tiles 0 and 1 (12 gloads); wait for tile 0 (6 oldest)
  stageA(0, 0); stageB(0, 0);
  stageA(1, 1); stageB(1, 1);
  asm volatile("s_waitcnt vmcnt(6)" ::: "memory");
  __builtin_amdgcn_s_barrier();

  int bcur = 0, bstage = 2;
  for (int t = 0; t < nk; ++t) {
    const bf16* __restrict__ Al = &As[bcur][0];
    const bf16* __restrict__ Bl = &Bs[bcur][0];
    const bool more = (t + 2 < nk);
    #pragma unroll
    for (int kc = 0; kc < 2; ++kc) {
      const int poff = kc ? pA1 : pA0;
      short8 a[4], b[4];
      #pragma unroll
      for (int i = 0; i < 4; ++i)
        a[i] = *(const short8*)(Al + (wr * 64 + i * 16 + l16) * 64 + poff);
      #pragma unroll
      for (int j = 0; j < 4; ++j)
        b[j] = *(const short8*)(Bl + (wc * 64 + j * 16 + l16) * 64 + poff);
      if (more) {
        if (kc == 0) stageA(bstage, t + 2);
        else         stageB(bstage, t + 2);
      }
      __builtin_amdgcn_s_barrier();
      __builtin_amdgcn_s_setprio(1);
      #pragma unroll
      for (int i = 0; i < 4; ++i)
        #pragma unroll
        for (int j = 0; j < 4; ++j)
          acc[i][j] = __builtin_amdgcn_mfma_f32_16x16x32_bf16(
              a[i], b[j], acc[i][j], 0, 0, 0);
      __builtin_amdgcn_s_setprio(0);
      if (kc == 1) {
        // tile boundary: counted wait -> tile t+1 landed, t+2 stays in flight
        if (more)            asm volatile("s_waitcnt vmcnt(6)" ::: "memory");
        else if (t + 1 < nk) asm volatile("s_waitcnt vmcnt(0)" ::: "memory");
      }
      __builtin_amdgcn_s_barrier();
    }
    bcur = (bcur == 2) ? 0 : bcur + 1;
    bstage = (bstage == 2) ? 0 : bstage + 1;
  }

  // epilogue: per-wave 64x64 block, frag (m,n): rows +quad*4, cols +l16
  const int rbase = by * 256 + wr * 64 + quad * 4;
  const int cbase = bx * 128 + wc * 64 + l16;
  #pragma unroll
  for (int m = 0; m < 4; ++m) {
    const int row = rbase + m * 16;
    #pragma unroll
    for (int n = 0; n < 4; ++n) {
      const int col = cbase + n * 16;
      floatx4 v = acc[m][n];
      if constexpr (MODE == 0) {
        bf16* C = (bf16*)Cv + (long)bz * sCz;
        const float bb = bias[col];
        #pragma unroll
        for (int r = 0; r < 4; ++r)
          C[(long)(row + r) * ldc + col] = __float2bfloat16(v[r] + bb);
      } else if constexpr (MODE == 1) {
        bf16* C = (bf16*)Cv + (long)bz * sCz;
        const float bb = bias[col];
        alignas(8) bf16 tmp[4];
        #pragma unroll
        for (int r = 0; r < 4; ++r) tmp[r] = __float2bfloat16(v[r] + bb);
        *(shortx4*)(C + (long)col * ldc + row) = *(const shortx4*)tmp;
      } else if constexpr (MODE == 2) {
        bf16* C = (bf16*)Cv + (long)bz * sCz;
        #pragma unroll
        for (int r = 0; r < 4; ++r)
          C[(long)(row + r) * ldc + col] = __float2bfloat16(v[r] * scale);
      } else {  // MODE 4
        float* C = (float*)Cv + (long)bz * sCz;
        const float bb = bias[col];
        floatx4 o_;
        #pragma unroll
        for (int r = 0; r < 4; ++r) o_[r] = v[r] + bb;
        *(floatx4*)(C + (long)col * ldc + row) = o_;
      }
    }
  }
}

// ---------------------------------------------------------------------------
// In-place row softmax over bf16 rows of length 4096. One block per row.
// ---------------------------------------------------------------------------
__global__ __launch_bounds__(256) void softmax_rows(bf16* __restrict__ sim) {
  bf16* p = sim + (long)blockIdx.y * ((long)SEQ * SEQ) + (long)blockIdx.x * SEQ;
  uint4* p4 = (uint4*)p;
  const int t = threadIdx.x;
  union U { uint4 u; ushort h[8]; } d[2];
  d[0].u = p4[t];
  d[1].u = p4[t + 256];
  float v[16];
  float mx = -3.0e38f;
  #pragma unroll
  for (int i = 0; i < 16; ++i) {
    v[i] = __uint_as_float(((unsigned)d[i >> 3].h[i & 7]) << 16);
    mx = fmaxf(mx, v[i]);
  }
  #pragma unroll
  for (int o = 32; o > 0; o >>= 1) mx = fmaxf(mx, __shfl_xor(mx, o));
  __shared__ float redmax[4], redsum[4];
  if ((t & 63) == 0) redmax[t >> 6] = mx;
  __syncthreads();
  mx = fmaxf(fmaxf(redmax[0], redmax[1]), fmaxf(redmax[2], redmax[3]));
  float sum = 0.f;
  #pragma unroll
  for (int i = 0; i < 16; ++i) {
    v[i] = __expf(v[i] - mx);
    sum += v[i];
  }
  #pragma unroll
  for (int o = 32; o > 0; o >>= 1) sum += __shfl_xor(sum, o);
  if ((t & 63) == 0) redsum[t >> 6] = sum;
  __syncthreads();
  sum = redsum[0] + redsum[1] + redsum[2] + redsum[3];
  const float inv = 1.0f / sum;
  union Hb { __hip_bfloat16 h; ushort u; };
  #pragma unroll
  for (int i = 0; i < 16; ++i) {
    Hb hb;
    hb.h = __float2bfloat16(v[i] * inv);
    d[i >> 3].h[i & 7] = hb.u;
  }
  p4[t] = d[0].u;
  p4[t + 256] = d[1].u;
}

// ---------------------------------------------------------------------------
extern "C" void kernel_launch(void* const* d_in, const int* in_sizes, int n_in,
                              void* d_out, int out_size, void* d_ws,
                              size_t ws_size, hipStream_t stream) {
  const float* q  = (const float*)d_in[0];
  const float* Wq = (const float*)d_in[1];
  const float* bq = (const float*)d_in[2];
  const float* Wk = (const float*)d_in[3];
  const float* bk = (const float*)d_in[4];
  const float* Wv = (const float*)d_in[5];
  const float* bv = (const float*)d_in[6];
  const float* Wo = (const float*)d_in[7];
  const float* bo = (const float*)d_in[8];
  float* out = (float*)d_out;

  bf16* ws = (bf16*)d_ws;
  const long WSZ = (long)DM * CH;         // 262144 elems per weight matrix
  const long XSZ = (long)SEQ * CH;        // 2097152 elems per batch
  const long SSZ = (long)SEQ * SEQ;       // 16777216 elems per batch
  bf16* Wqb = ws;
  bf16* Wkb = Wqb + WSZ;
  bf16* Wvb = Wqb + 2 * WSZ;
  bf16* Wob = Wqb + 3 * WSZ;
  bf16* xT  = Wqb + 4 * WSZ;
  bf16* Qb  = xT + BATCH * XSZ;
  bf16* Kb  = Qb + BATCH * XSZ;
  bf16* Vt  = Kb + BATCH * XSZ;   // (b, d, s) layout
  bf16* Ob  = Vt + BATCH * XSZ;
  bf16* Sim = Ob + BATCH * XSZ;   // (b, s, t) bf16, softmaxed in place

  cvt_weights<<<dim3(WSZ / 256, 4), 256, 0, stream>>>(Wq, Wk, Wv, Wo, ws);
  transpose_cvt<<<dim3(SEQ / 64, CH / 64, BATCH), 256, 0, stream>>>(q, xT);

  // Q = xT * Wq^T + bq  (4096x512x512), bf16 out, row-major [s][d]
  gemm_bn128<0><<<dim3(4, 16, BATCH), 512, 0, stream>>>(
      xT, XSZ, Wqb, 0, Qb, XSZ, bq, 1.f, CH, DM);
  gemm_bn128<0><<<dim3(4, 16, BATCH), 512, 0, stream>>>(
      xT, XSZ, Wkb, 0, Kb, XSZ, bk, 1.f, CH, DM);
  // V stored transposed: Vt[d][s]
  gemm_bn128<1><<<dim3(4, 16, BATCH), 512, 0, stream>>>(
      xT, XSZ, Wvb, 0, Vt, XSZ, bv, 1.f, CH, SEQ);
  // sim = Q*K^T * scale (4096x4096x512): 256x256 tile, counted-vmcnt pipeline
  gemm_qk<<<dim3(16, 16, BATCH), 512, 0, stream>>>(
      Qb, XSZ, Kb, XSZ, Sim, SSZ, 0.04419417382415922f, CH, SEQ);
  softmax_rows<<<dim3(SEQ, BATCH), 256, 0, stream>>>(Sim);
  // o = P * V  (4096x512x4096): 256x128 tile, deep K, triple-buffered
  gemm_bn128<2><<<dim3(4, 16, BATCH), 512, 0, stream>>>(
      Sim, SSZ, Vt, XSZ, Ob, XSZ, nullptr, 1.0f, SEQ, DM);
  // y = o * Wo^T + bo, stored transposed into d_out as (b, c, s) fp32
  gemm_bn128<4><<<dim3(4, 16, BATCH), 512, 0, stream>>>(
      Ob, XSZ, Wob, 0, out, XSZ, bo, 1.f, DM, SEQ);
}